// Round 1
// baseline (285.112 us; speedup 1.0000x reference)
//
#include <hip/hip_runtime.h>

// Problem constants
#define BATCH 4096
#define INF   2048
#define OUTF  2048
#define KK    4096   // concatenated K = 2*INF

typedef __attribute__((ext_vector_type(8))) short bf16x8;
typedef __attribute__((ext_vector_type(4))) float f32x4;

// float -> bf16 bits, round-to-nearest-even (inputs are finite normals)
__device__ inline unsigned short f2bf(float f) {
  unsigned int u = __float_as_uint(f);
  u += 0x7fffu + ((u >> 16) & 1u);
  return (unsigned short)(u >> 16);
}

// 16B async global->LDS. LDS dest must be wave-uniform; HW writes base + lane*16.
__device__ inline void gld16(const void* g, void* l) {
  __builtin_amdgcn_global_load_lds(
      (const __attribute__((address_space(1))) void*)g,
      (__attribute__((address_space(3))) void*)l,
      16, 0, 0);
}

// Pack A = [x_re | x_im] rows (4096 x 4096 bf16). 1 thread = 4 cols of each half.
__global__ __launch_bounds__(256) void pack_a(const float* __restrict__ xr,
                                              const float* __restrict__ xi,
                                              unsigned short* __restrict__ A) {
  int t = blockIdx.x * 256 + threadIdx.x;      // 0 .. 4096*512
  float4 vr = ((const float4*)xr)[t];
  float4 vi = ((const float4*)xi)[t];
  int b  = t >> 9;          // row
  int c4 = t & 511;         // float4 col within 2048
  ushort4 sr = make_ushort4(f2bf(vr.x), f2bf(vr.y), f2bf(vr.z), f2bf(vr.w));
  ushort4 si = make_ushort4(f2bf(vi.x), f2bf(vi.y), f2bf(vi.z), f2bf(vi.w));
  ushort4* A4 = (ushort4*)A;                   // row stride = 1024 ushort4
  A4[b * 1024 + c4]       = sr;
  A4[b * 1024 + 512 + c4] = si;
}

// Pack Bre = [w_re | -w_im], Bim = [w_im | w_re]  (2048 x 4096 bf16 each)
__global__ __launch_bounds__(256) void pack_b(const float* __restrict__ wr,
                                              const float* __restrict__ wi,
                                              unsigned short* __restrict__ Br,
                                              unsigned short* __restrict__ Bi) {
  int t = blockIdx.x * 256 + threadIdx.x;      // 0 .. 2048*512
  float4 vr = ((const float4*)wr)[t];
  float4 vi = ((const float4*)wi)[t];
  int o  = t >> 9;
  int c4 = t & 511;
  ushort4 srp = make_ushort4(f2bf(vr.x),  f2bf(vr.y),  f2bf(vr.z),  f2bf(vr.w));
  ushort4 sin = make_ushort4(f2bf(-vi.x), f2bf(-vi.y), f2bf(-vi.z), f2bf(-vi.w));
  ushort4 sip = make_ushort4(f2bf(vi.x),  f2bf(vi.y),  f2bf(vi.z),  f2bf(vi.w));
  ushort4* Br4 = (ushort4*)Br;
  ushort4* Bi4 = (ushort4*)Bi;
  Br4[o * 1024 + c4]       = srp;   // w_re
  Br4[o * 1024 + 512 + c4] = sin;   // -w_im
  Bi4[o * 1024 + c4]       = sip;   // w_im
  Bi4[o * 1024 + 512 + c4] = srp;   // w_re
}

// Fused complex GEMM: out[b,o,0] = A.Bre^T, out[b,o,1] = A.Bim^T
// 128x128 block tile, 4 waves (2x2), each 64x64 via 4x4 mfma 16x16x32 bf16, BK=32.
__global__ __launch_bounds__(256, 2) void cgemm(const unsigned short* __restrict__ A,
                                                const unsigned short* __restrict__ Br,
                                                const unsigned short* __restrict__ Bi,
                                                float* __restrict__ out) {
  __shared__ unsigned short sA[128 * 32];   // 8 KB
  __shared__ unsigned short sBr[128 * 32];  // 8 KB
  __shared__ unsigned short sBi[128 * 32];  // 8 KB

  const int tid  = threadIdx.x;
  const int wid  = tid >> 6;
  const int lane = tid & 63;
  const int lrow = lane & 15;   // fragment row/col within 16
  const int lhi  = lane >> 4;   // quad index 0..3
  const int wm   = wid >> 1;    // wave row 0..1
  const int wn   = wid & 1;     // wave col 0..1

  const int bn0 = blockIdx.x * 128;   // out-feature tile
  const int bm0 = blockIdx.y * 128;   // batch tile

  // Staging: chunk ch = p*256 + tid covers LDS bytes ch*16; row = ch>>2, col8 = (ch&3)*8
  const int srow = tid >> 2;          // 0..63 (p=0), +64 for p=1
  const int scol = (tid & 3) * 8;

  const unsigned short* gA  = A  + (size_t)(bm0 + srow) * KK + scol;
  const unsigned short* gBr = Br + (size_t)(bn0 + srow) * KK + scol;
  const unsigned short* gBi = Bi + (size_t)(bn0 + srow) * KK + scol;

  char* lA  = (char*)sA  + wid * 1024;   // wave-uniform LDS bases
  char* lBr = (char*)sBr + wid * 1024;
  char* lBi = (char*)sBi + wid * 1024;

  f32x4 accre[4][4], accim[4][4];
  const f32x4 zz = {0.f, 0.f, 0.f, 0.f};
#pragma unroll
  for (int i = 0; i < 4; ++i)
#pragma unroll
    for (int j = 0; j < 4; ++j) { accre[i][j] = zz; accim[i][j] = zz; }

  for (int kt = 0; kt < KK; kt += 32) {
    // stage 3 tiles of 128x32 bf16 (8 KB each) = 6 x 16B per thread
    gld16(gA + kt,                 lA);
    gld16(gA + kt + (size_t)64 * KK, lA + 4096);
    gld16(gBr + kt,                 lBr);
    gld16(gBr + kt + (size_t)64 * KK, lBr + 4096);
    gld16(gBi + kt,                 lBi);
    gld16(gBi + kt + (size_t)64 * KK, lBi + 4096);
    __syncthreads();   // drains vmcnt -> LDS valid

    bf16x8 af[4], brf[4], bif[4];
#pragma unroll
    for (int i = 0; i < 4; ++i) {
      af[i]  = *(const bf16x8*)&sA[(wm * 64 + i * 16 + lrow) * 32 + lhi * 8];
      brf[i] = *(const bf16x8*)&sBr[(wn * 64 + i * 16 + lrow) * 32 + lhi * 8];
      bif[i] = *(const bf16x8*)&sBi[(wn * 64 + i * 16 + lrow) * 32 + lhi * 8];
    }
#pragma unroll
    for (int i = 0; i < 4; ++i)
#pragma unroll
      for (int j = 0; j < 4; ++j) {
        accre[i][j] = __builtin_amdgcn_mfma_f32_16x16x32_bf16(af[i], brf[j], accre[i][j], 0, 0, 0);
        accim[i][j] = __builtin_amdgcn_mfma_f32_16x16x32_bf16(af[i], bif[j], accim[i][j], 0, 0, 0);
      }
    __syncthreads();   // protect LDS from next stage
  }

  // Epilogue: C/D layout col=lane&15, row=quad*4+reg. Write interleaved {re,im}.
  const int row0 = bm0 + wm * 64 + lhi * 4;
  const int col0 = bn0 + wn * 64 + lrow;
#pragma unroll
  for (int i = 0; i < 4; ++i)
#pragma unroll
    for (int j = 0; j < 4; ++j)
#pragma unroll
      for (int r = 0; r < 4; ++r) {
        int row = row0 + i * 16 + r;
        int col = col0 + j * 16;
        float2 v = make_float2(accre[i][j][r], accim[i][j][r]);
        *(float2*)&out[((size_t)row * OUTF + col) * 2] = v;
      }
}

// Safety fallback if workspace is too small: fp32 vector path (slow but correct)
__global__ __launch_bounds__(256) void naive_cx(const float* __restrict__ xr,
                                                const float* __restrict__ xi,
                                                const float* __restrict__ wr,
                                                const float* __restrict__ wi,
                                                float* __restrict__ out) {
  int t = blockIdx.x * 256 + threadIdx.x;   // over BATCH*OUTF
  int b = t >> 11, o = t & 2047;
  const float* xrb = xr + (size_t)b * INF;
  const float* xib = xi + (size_t)b * INF;
  const float* wrb = wr + (size_t)o * INF;
  const float* wib = wi + (size_t)o * INF;
  float are = 0.f, aim = 0.f;
  for (int i = 0; i < INF; ++i) {
    float a = xrb[i], c = xib[i], p = wrb[i], q = wib[i];
    are += a * p - c * q;
    aim += a * q + c * p;
  }
  out[(size_t)t * 2 + 0] = are;
  out[(size_t)t * 2 + 1] = aim;
}

extern "C" void kernel_launch(void* const* d_in, const int* in_sizes, int n_in,
                              void* d_out, int out_size, void* d_ws, size_t ws_size,
                              hipStream_t stream) {
  const float* xr = (const float*)d_in[0];
  const float* xi = (const float*)d_in[1];
  const float* wr = (const float*)d_in[2];
  const float* wi = (const float*)d_in[3];
  float* out = (float*)d_out;

  const size_t need = (size_t)(4096ULL * 4096 + 2 * 2048ULL * 4096) * 2;  // 64 MiB
  if (ws_size < need) {
    naive_cx<<<(BATCH * OUTF) / 256, 256, 0, stream>>>(xr, xi, wr, wi, out);
    return;
  }

  unsigned short* A  = (unsigned short*)d_ws;                 // 4096 x 4096 bf16
  unsigned short* Br = A  + (size_t)4096 * 4096;              // 2048 x 4096 bf16
  unsigned short* Bi = Br + (size_t)2048 * 4096;              // 2048 x 4096 bf16

  pack_a<<<(BATCH * INF / 4) / 256, 256, 0, stream>>>(xr, xi, A);
  pack_b<<<(OUTF * INF / 4) / 256, 256, 0, stream>>>(wr, wi, Br, Bi);

  dim3 grid(OUTF / 128, BATCH / 128);   // 16 x 32 = 512 blocks
  cgemm<<<grid, 256, 0, stream>>>(A, Br, Bi, out);
}

// Round 2
// 252.126 us; speedup vs baseline: 1.1308x; 1.1308x over previous
//
#include <hip/hip_runtime.h>

// Problem constants
#define BATCH 4096
#define INF   2048
#define OUTF  2048

typedef __attribute__((ext_vector_type(8))) short bf16x8;
typedef __attribute__((ext_vector_type(4))) float f32x4;

// float -> bf16 bits, round-to-nearest-even
__device__ inline unsigned short f2bf(float f) {
  unsigned int u = __float_as_uint(f);
  u += 0x7fffu + ((u >> 16) & 1u);
  return (unsigned short)(u >> 16);
}

// 16B async global->LDS. LDS dest is wave-uniform base; HW writes base + lane*16.
__device__ inline void gld16(const void* g, void* l) {
  __builtin_amdgcn_global_load_lds(
      (const __attribute__((address_space(1))) void*)g,
      (__attribute__((address_space(3))) void*)l,
      16, 0, 0);
}

// Fused pack: x_re,x_im (4096x2048) and w_re,w_im (2048x2048) fp32 -> bf16,
// plain row-major (no concatenation, no duplication).
__global__ __launch_bounds__(256) void pack_all(const float* __restrict__ xr,
                                                const float* __restrict__ xi,
                                                const float* __restrict__ wr,
                                                const float* __restrict__ wi,
                                                unsigned short* __restrict__ Xre,
                                                unsigned short* __restrict__ Xim,
                                                unsigned short* __restrict__ Wr,
                                                unsigned short* __restrict__ Wi) {
  const int XCH = (BATCH * INF) / 8;   // 1048576 ushort8 chunks for each x matrix
  int t = blockIdx.x * 256 + threadIdx.x;
  const float4 *s0, *s1;
  bf16x8 *d0, *d1;
  int idx;
  if (t < XCH) {
    idx = t;
    s0 = (const float4*)xr; s1 = (const float4*)xi;
    d0 = (bf16x8*)Xre;      d1 = (bf16x8*)Xim;
  } else {
    idx = t - XCH;                      // < (OUTF*INF)/8 = 524288
    s0 = (const float4*)wr; s1 = (const float4*)wi;
    d0 = (bf16x8*)Wr;       d1 = (bf16x8*)Wi;
  }
  float4 a0 = s0[2 * idx], a1 = s0[2 * idx + 1];
  float4 b0 = s1[2 * idx], b1 = s1[2 * idx + 1];
  bf16x8 v0, v1;
  v0[0] = (short)f2bf(a0.x); v0[1] = (short)f2bf(a0.y);
  v0[2] = (short)f2bf(a0.z); v0[3] = (short)f2bf(a0.w);
  v0[4] = (short)f2bf(a1.x); v0[5] = (short)f2bf(a1.y);
  v0[6] = (short)f2bf(a1.z); v0[7] = (short)f2bf(a1.w);
  v1[0] = (short)f2bf(b0.x); v1[1] = (short)f2bf(b0.y);
  v1[2] = (short)f2bf(b0.z); v1[3] = (short)f2bf(b0.w);
  v1[4] = (short)f2bf(b1.x); v1[5] = (short)f2bf(b1.y);
  v1[6] = (short)f2bf(b1.z); v1[7] = (short)f2bf(b1.w);
  d0[idx] = v0;
  d1[idx] = v1;
}

// Fused complex GEMM over K=2048 with 4 raw tiles.
// out[b,o,0] = Xre.Wr^T - Xim.Wi^T ; out[b,o,1] = Xre.Wi^T + Xim.Wr^T
// 128x128 block tile, 4 waves (2x2), each 64x64 via 4x4 mfma 16x16x32 bf16.
// BK=64 staged as two 32-wide halves inside one barrier pair (128 MFMA/barrier).
// LDS chunk swizzle: c_lds = c ^ s(row), s(row)=(row&3)^((row>>2)&3) -> 2-way banks.
__global__ __launch_bounds__(256, 2) void cgemm(const unsigned short* __restrict__ Xre,
                                                const unsigned short* __restrict__ Xim,
                                                const unsigned short* __restrict__ Wr,
                                                const unsigned short* __restrict__ Wi,
                                                float* __restrict__ out) {
  __shared__ unsigned short sXre[128 * 64];  // 16 KB each, 64 KB total
  __shared__ unsigned short sXim[128 * 64];
  __shared__ unsigned short sWr[128 * 64];
  __shared__ unsigned short sWi[128 * 64];

  const int tid  = threadIdx.x;
  const int wid  = tid >> 6;
  const int lane = tid & 63;
  const int lrow = lane & 15;
  const int lhi  = lane >> 4;
  const int wm   = wid >> 1;
  const int wn   = wid & 1;

  const int bn0 = blockIdx.x * 128;   // out-feature tile
  const int bm0 = blockIdx.y * 128;   // batch tile

  // Staging map: chunk ch = p*256+tid -> LDS(row=ch>>2, c=ch&3); source column
  // chunk swizzled so LDS(r,c) holds global chunk c^s(r).
  const int srow = tid >> 2;                        // 0..63 (p=0), +64 for p=1
  const int sc   = tid & 3;
  const int ss   = (srow & 3) ^ ((srow >> 2) & 3);  // same for srow and srow+64
  const int scol = (sc ^ ss) * 8;                   // shorts within 32-wide half

  const unsigned short* gXre = Xre + (size_t)(bm0 + srow) * INF + scol;
  const unsigned short* gXim = Xim + (size_t)(bm0 + srow) * INF + scol;
  const unsigned short* gWr  = Wr  + (size_t)(bn0 + srow) * INF + scol;
  const unsigned short* gWi  = Wi  + (size_t)(bn0 + srow) * INF + scol;

  const int ldsoff = wid * 1024;   // bytes; + p*4096 + h*8192

  // Fragment read: logical k-chunk lhi -> LDS chunk lhi^s(row); s(row)==slane
  // for row = wm*64+i*16+lrow (multiples of 16 drop out).
  const int slane  = (lrow & 3) ^ ((lrow >> 2) & 3);
  const int kchunk = (lhi ^ slane) * 8;             // shorts

  f32x4 accre[4][4], accim[4][4];
  const f32x4 zz = {0.f, 0.f, 0.f, 0.f};
#pragma unroll
  for (int i = 0; i < 4; ++i)
#pragma unroll
    for (int j = 0; j < 4; ++j) { accre[i][j] = zz; accim[i][j] = zz; }

  const bf16x8 SGN = {(short)0x8000, (short)0x8000, (short)0x8000, (short)0x8000,
                      (short)0x8000, (short)0x8000, (short)0x8000, (short)0x8000};

  for (int kt = 0; kt < INF; kt += 64) {
#pragma unroll
    for (int h = 0; h < 2; ++h) {
      const int go = kt + h * 32;
      const int lo = h * 8192 + ldsoff;
      gld16(gXre + go,                  (char*)sXre + lo);
      gld16(gXre + go + (size_t)64 * INF, (char*)sXre + lo + 4096);
      gld16(gXim + go,                  (char*)sXim + lo);
      gld16(gXim + go + (size_t)64 * INF, (char*)sXim + lo + 4096);
      gld16(gWr + go,                   (char*)sWr + lo);
      gld16(gWr + go + (size_t)64 * INF,  (char*)sWr + lo + 4096);
      gld16(gWi + go,                   (char*)sWi + lo);
      gld16(gWi + go + (size_t)64 * INF,  (char*)sWi + lo + 4096);
    }
    __syncthreads();

#pragma unroll
    for (int h = 0; h < 2; ++h) {
      const int hb = h * 4096;  // shorts
      bf16x8 xr_[4], xi_[4], wr_[4], wi_[4], wn_[4];
#pragma unroll
      for (int i = 0; i < 4; ++i) {
        xr_[i] = *(const bf16x8*)&sXre[hb + (wm * 64 + i * 16 + lrow) * 32 + kchunk];
        xi_[i] = *(const bf16x8*)&sXim[hb + (wm * 64 + i * 16 + lrow) * 32 + kchunk];
        wr_[i] = *(const bf16x8*)&sWr [hb + (wn * 64 + i * 16 + lrow) * 32 + kchunk];
        wi_[i] = *(const bf16x8*)&sWi [hb + (wn * 64 + i * 16 + lrow) * 32 + kchunk];
      }
#pragma unroll
      for (int j = 0; j < 4; ++j) wn_[j] = wi_[j] ^ SGN;   // -w_im fragments
#pragma unroll
      for (int i = 0; i < 4; ++i)
#pragma unroll
        for (int j = 0; j < 4; ++j) {
          accre[i][j] = __builtin_amdgcn_mfma_f32_16x16x32_bf16(xr_[i], wr_[j], accre[i][j], 0, 0, 0);
          accre[i][j] = __builtin_amdgcn_mfma_f32_16x16x32_bf16(xi_[i], wn_[j], accre[i][j], 0, 0, 0);
          accim[i][j] = __builtin_amdgcn_mfma_f32_16x16x32_bf16(xr_[i], wi_[j], accim[i][j], 0, 0, 0);
          accim[i][j] = __builtin_amdgcn_mfma_f32_16x16x32_bf16(xi_[i], wr_[j], accim[i][j], 0, 0, 0);
        }
    }
    __syncthreads();
  }

  // Epilogue: C/D layout col=lane&15, row=(lane>>4)*4+reg. Interleaved {re,im}.
  const int row0 = bm0 + wm * 64 + lhi * 4;
  const int col0 = bn0 + wn * 64 + lrow;
#pragma unroll
  for (int i = 0; i < 4; ++i)
#pragma unroll
    for (int j = 0; j < 4; ++j)
#pragma unroll
      for (int r = 0; r < 4; ++r) {
        int row = row0 + i * 16 + r;
        int col = col0 + j * 16;
        float2 v = make_float2(accre[i][j][r], accim[i][j][r]);
        *(float2*)&out[((size_t)row * OUTF + col) * 2] = v;
      }
}

// Safety fallback if workspace too small: fp32 vector path (slow but correct)
__global__ __launch_bounds__(256) void naive_cx(const float* __restrict__ xr,
                                                const float* __restrict__ xi,
                                                const float* __restrict__ wr,
                                                const float* __restrict__ wi,
                                                float* __restrict__ out) {
  int t = blockIdx.x * 256 + threadIdx.x;
  int b = t >> 11, o = t & 2047;
  const float* xrb = xr + (size_t)b * INF;
  const float* xib = xi + (size_t)b * INF;
  const float* wrb = wr + (size_t)o * INF;
  const float* wib = wi + (size_t)o * INF;
  float are = 0.f, aim = 0.f;
  for (int i = 0; i < INF; ++i) {
    float a = xrb[i], c = xib[i], p = wrb[i], q = wib[i];
    are += a * p - c * q;
    aim += a * q + c * p;
  }
  out[(size_t)t * 2 + 0] = are;
  out[(size_t)t * 2 + 1] = aim;
}

extern "C" void kernel_launch(void* const* d_in, const int* in_sizes, int n_in,
                              void* d_out, int out_size, void* d_ws, size_t ws_size,
                              hipStream_t stream) {
  const float* xr = (const float*)d_in[0];
  const float* xi = (const float*)d_in[1];
  const float* wr = (const float*)d_in[2];
  const float* wi = (const float*)d_in[3];
  float* out = (float*)d_out;

  const size_t nx = (size_t)BATCH * INF;   // 8M elements per x matrix
  const size_t nw = (size_t)OUTF * INF;    // 4M elements per w matrix
  const size_t need = (2 * nx + 2 * nw) * sizeof(unsigned short);  // 48 MiB

  if (ws_size < need) {
    naive_cx<<<(BATCH * OUTF) / 256, 256, 0, stream>>>(xr, xi, wr, wi, out);
    return;
  }

  unsigned short* Xre = (unsigned short*)d_ws;
  unsigned short* Xim = Xre + nx;
  unsigned short* Wr  = Xim + nx;
  unsigned short* Wi  = Wr + nw;

  const int total_chunks = (int)((2 * nx) / 16 + (2 * nw) / 16);  // handled pairwise
  // pack_all: one thread per ushort8 chunk of each (re,im) pair
  const int grid_pack = (int)((nx / 8 + nw / 8) / 256);           // 6144
  pack_all<<<grid_pack, 256, 0, stream>>>(xr, xi, wr, wi, Xre, Xim, Wr, Wi);
  (void)total_chunks;

  dim3 grid(OUTF / 128, BATCH / 128);   // 16 x 32 = 512 blocks
  cgemm<<<grid, 256, 0, stream>>>(Xre, Xim, Wr, Wi, out);
}